// Round 7
// baseline (34.232 us; speedup 1.0000x reference)
//
#include <hip/hip_runtime.h>
#include <hip/hip_bf16.h>
#include <math.h>

// LinearAttention: X = Qf @ (Kf^T @ Vm) per (b,h); B=2 H=12 N=4096 D=64 fp32.
// Qf=(elu(Q)+1)*s ; Kf=(elu(K)+1)*m*s ; Vm=V*m ; s = 4096^-0.25 = 0.125.
//
// 3-kernel MFMA pipeline (bf16 in, fp32 accum), fragments straight from global.
// pass1 geometry: 768 blocks x 128 threads = exactly 3 blocks/CU (balanced);
// each block reduces its 2 waves in LDS and writes ONE 64x64 fp32 partial.

#define BH_TOT 24
#define NROWS 4096
#define DD 64

typedef __attribute__((ext_vector_type(8))) short bf16x8;   // 8 x bf16
typedef __attribute__((ext_vector_type(4))) float f32x4;    // MFMA C/D frag

__device__ __forceinline__ float elu1(float x) {
    return x > 0.0f ? x + 1.0f : __expf(x);
}
__device__ __forceinline__ short f2bf(float x) {
    __hip_bfloat16 h = __float2bfloat16(x);
    return *reinterpret_cast<short*>(&h);
}

// ---------------- Pass 1: per-block partial KtV ----------------
// grid (24, SLABS), block 128 (2 waves). Wave handles chunksPerWave*32 rows.
__global__ __launch_bounds__(128) void la_pass1(
        const float* __restrict__ K, const float* __restrict__ V,
        const float* __restrict__ mask, float* __restrict__ partial,
        float scale, int chunksPerWave) {
    const int bh   = blockIdx.x;
    const int slab = blockIdx.y;
    const int wave = threadIdx.x >> 6;    // 0..1
    const int lane = threadIdx.x & 63;
    const int g = lane >> 4, rg = g * 8, cl = lane & 15;

    const float* __restrict__ Kp = K + (size_t)bh * NROWS * DD;
    const float* __restrict__ Vp = V + (size_t)bh * NROWS * DD;
    const float* __restrict__ mp = mask + (size_t)(bh / 12) * NROWS;

    f32x4 acc[4][4];
#pragma unroll
    for (int i = 0; i < 4; ++i)
#pragma unroll
        for (int j = 0; j < 4; ++j) acc[i][j] = (f32x4)0.0f;

    const int rowsPerBlock = chunksPerWave * 64;
    const int n0 = slab * rowsPerBlock + wave * chunksPerWave * 32;

#pragma unroll 1
    for (int c = 0; c < chunksPerWave; ++c) {
        const int nb = n0 + c * 32 + rg;              // this lane's 8-row group
        const float* kb = Kp + (size_t)nb * DD + cl;
        const float* vb = Vp + (size_t)nb * DD + cl;
        float mrow[8], kr[8][4], vr[8][4];
#pragma unroll
        for (int jj = 0; jj < 8; ++jj) {
            mrow[jj] = mp[nb + jj];
#pragma unroll
            for (int i = 0; i < 4; ++i) {
                kr[jj][i] = kb[jj * DD + i * 16];     // imm-offset dword loads
                vr[jj][i] = vb[jj * DD + i * 16];
            }
        }
        bf16x8 af[4], bv[4];
#pragma unroll
        for (int i = 0; i < 4; ++i)
#pragma unroll
            for (int jj = 0; jj < 8; ++jj) {
                af[i][jj] = f2bf(elu1(kr[jj][i]) * (mrow[jj] * scale));
                bv[i][jj] = f2bf(vr[jj][i] * mrow[jj]);
            }
#pragma unroll
        for (int i = 0; i < 4; ++i)
#pragma unroll
            for (int j = 0; j < 4; ++j)
                acc[i][j] = __builtin_amdgcn_mfma_f32_16x16x32_bf16(
                                af[i], bv[j], acc[i][j], 0, 0, 0);
    }

    // cross-wave reduce in LDS (stride 66 => uniform 2-way banks = free)
    __shared__ float red[DD * 66];
#define RIDX(i, r, j) ((16 * (i) + 4 * g + (r)) * 66 + 16 * (j) + cl)
    if (wave == 1) {
#pragma unroll
        for (int i = 0; i < 4; ++i)
#pragma unroll
            for (int j = 0; j < 4; ++j)
#pragma unroll
                for (int r = 0; r < 4; ++r) red[RIDX(i, r, j)] = acc[i][j][r];
    }
    __syncthreads();
    if (wave == 0) {
        float* out = partial + ((size_t)bh * gridDim.y + slab) * (DD * DD);
#pragma unroll
        for (int i = 0; i < 4; ++i)
#pragma unroll
            for (int j = 0; j < 4; ++j)
#pragma unroll
                for (int r = 0; r < 4; ++r)
                    out[(16 * i + 4 * g + r) * DD + 16 * j + cl]
                        = acc[i][j][r] + red[RIDX(i, r, j)];
    }
#undef RIDX
}

// ---------------- Pass 2: reduce partials -> bf16 ktvT[e][d] ----------------
// grid (24, 4), block 256; thread owns float4 (d = f4>>4, e = (f4&15)*4 ..+3)
__global__ __launch_bounds__(256) void la_pass2(
        const float* __restrict__ partial, __hip_bfloat16* __restrict__ ktvT,
        int nw) {
    const int bh = blockIdx.x;
    const int f4 = blockIdx.y * 256 + threadIdx.x;     // 0..1023
    const f32x4* base = (const f32x4*)(partial + (size_t)bh * nw * DD * DD) + f4;
    f32x4 s = (f32x4)0.0f;
#pragma unroll 8
    for (int w = 0; w < nw; ++w)
        s += base[(size_t)w * (DD * DD / 4)];
    const int d = f4 >> 4, e0 = (f4 & 15) * 4;
    __hip_bfloat16* o = ktvT + (size_t)bh * DD * DD + d;
#pragma unroll
    for (int q = 0; q < 4; ++q)
        o[(size_t)(e0 + q) * DD] = __float2bfloat16(s[q]);
}

// ---------------- Pass 3: X = Qf @ KtV ----------------
// grid (24, 32), block 256; wave handles 32 rows.
__global__ __launch_bounds__(256) void la_pass3(
        const float* __restrict__ Q, const __hip_bfloat16* __restrict__ ktvT,
        float* __restrict__ X, float scale) {
    const int bh   = blockIdx.x;
    const int wave = threadIdx.x >> 6;
    const int lane = threadIdx.x & 63;
    const int n0   = blockIdx.y * 128 + wave * 32;
    const int rg   = (lane >> 4) * 8;
    const int cl   = lane & 15;

    // B-frag(c,j): B[k=32c+rg+jj][col=16j+cl] = ktvT[16j+cl][32c+rg+jj] -> 16B
    bf16x8 bfr[2][4];
#pragma unroll
    for (int c2 = 0; c2 < 2; ++c2)
#pragma unroll
        for (int j = 0; j < 4; ++j) {
            const __hip_bfloat16* p = ktvT + (size_t)bh * DD * DD
                                      + (size_t)(16 * j + cl) * DD + 32 * c2 + rg;
            bfr[c2][j] = *reinterpret_cast<const bf16x8*>(p);
        }

    // A-frag(i,c): A[row=cl][k=rg+jj] = Qf[n0+16i+cl][32c+rg+jj] -> 2x float4
    const float* Qp = Q + (size_t)bh * NROWS * DD;
    bf16x8 afr[2][2];
#pragma unroll
    for (int i = 0; i < 2; ++i)
#pragma unroll
        for (int c2 = 0; c2 < 2; ++c2) {
            const float* qp = Qp + (size_t)(n0 + 16 * i + cl) * DD + 32 * c2 + rg;
            float4 q0 = ((const float4*)qp)[0];
            float4 q1 = ((const float4*)qp)[1];
            bf16x8 a;
            a[0] = f2bf(elu1(q0.x) * scale); a[1] = f2bf(elu1(q0.y) * scale);
            a[2] = f2bf(elu1(q0.z) * scale); a[3] = f2bf(elu1(q0.w) * scale);
            a[4] = f2bf(elu1(q1.x) * scale); a[5] = f2bf(elu1(q1.y) * scale);
            a[6] = f2bf(elu1(q1.z) * scale); a[7] = f2bf(elu1(q1.w) * scale);
            afr[i][c2] = a;
        }

    f32x4 acc[2][4];
#pragma unroll
    for (int i = 0; i < 2; ++i)
#pragma unroll
        for (int j = 0; j < 4; ++j) acc[i][j] = (f32x4)0.0f;

#pragma unroll
    for (int i = 0; i < 2; ++i)
#pragma unroll
        for (int j = 0; j < 4; ++j) {
            acc[i][j] = __builtin_amdgcn_mfma_f32_16x16x32_bf16(
                            afr[i][0], bfr[0][j], acc[i][j], 0, 0, 0);
            acc[i][j] = __builtin_amdgcn_mfma_f32_16x16x32_bf16(
                            afr[i][1], bfr[1][j], acc[i][j], 0, 0, 0);
        }

    float* Xp = X + (size_t)bh * NROWS * DD;
#pragma unroll
    for (int i = 0; i < 2; ++i)
#pragma unroll
        for (int j = 0; j < 4; ++j)
#pragma unroll
            for (int r = 0; r < 4; ++r)
                Xp[(size_t)(n0 + 16 * i + (lane >> 4) * 4 + r) * DD + 16 * j + cl]
                    = acc[i][j][r];
}

extern "C" void kernel_launch(void* const* d_in, const int* in_sizes, int n_in,
                              void* d_out, int out_size, void* d_ws, size_t ws_size,
                              hipStream_t stream) {
    const float* Q    = (const float*)d_in[0];
    const float* K    = (const float*)d_in[1];
    const float* V    = (const float*)d_in[2];
    const float* mask = (const float*)d_in[3];
    float* X = (float*)d_out;

    const float scale = 0.125f;   // 4096^-0.25 exactly

    // slabs per head: prefer 32 (768 blocks = 3.0 blocks/CU), shrink if ws tight
    int slabs = 32;
    while (slabs > 4 &&
           (size_t)BH_TOT * slabs * DD * DD * 4 + (size_t)BH_TOT * DD * DD * 2 > ws_size)
        slabs >>= 1;
    const int chunksPerWave = NROWS / (slabs * 64);

    float* partial = (float*)d_ws;
    __hip_bfloat16* ktvT =
        (__hip_bfloat16*)((char*)d_ws + (size_t)BH_TOT * slabs * DD * DD * 4);

    la_pass1<<<dim3(BH_TOT, slabs), 128, 0, stream>>>(K, V, mask, partial,
                                                      scale, chunksPerWave);
    la_pass2<<<dim3(BH_TOT, 4), 256, 0, stream>>>(partial, ktvT, slabs);
    la_pass3<<<dim3(BH_TOT, 32), 256, 0, stream>>>(Q, ktvT, X, scale);
}